// Round 15
// baseline (270.735 us; speedup 1.0000x reference)
//
#include <hip/hip_runtime.h>

// ---------- types ----------
typedef unsigned short u16;
typedef __bf16  bf16x8 __attribute__((ext_vector_type(8)));
typedef short   short8 __attribute__((ext_vector_type(8)));
typedef float   f32x4  __attribute__((ext_vector_type(4)));
typedef u16     u16x4  __attribute__((ext_vector_type(4)));

__device__ __forceinline__ u16 f2bf(float f) {
  unsigned b = __builtin_bit_cast(unsigned, f);
  b += 0x7fffu + ((b >> 16) & 1u);          // round-to-nearest-even
  return (u16)(b >> 16);
}
__device__ __forceinline__ float bf2f(u16 u) {
  return __builtin_bit_cast(float, (unsigned)u << 16);
}
__device__ __forceinline__ f32x4 mfma16(short8 a, short8 b, f32x4 c) {
  return __builtin_amdgcn_mfma_f32_16x16x32_bf16(
      __builtin_bit_cast(bf16x8, a), __builtin_bit_cast(bf16x8, b), c, 0, 0, 0);
}
__device__ __forceinline__ void gload_lds16(const void* g, void* l) {
  __builtin_amdgcn_global_load_lds(
      (const __attribute__((address_space(1))) void*)g,
      (__attribute__((address_space(3))) void*)l, 16, 0, 0);
}

#define VMCNT(n) asm volatile("s_waitcnt vmcnt(" #n ")" ::: "memory")
#define LGKMCNT(n) asm volatile("s_waitcnt lgkmcnt(" #n ")" ::: "memory")
#define MEMFENCE asm volatile("" ::: "memory")

// ---------- cast x -> bf16 ----------
__global__ __launch_bounds__(256) void castk(const float* __restrict__ in,
                                             u16* __restrict__ out, int n4) {
  int i = blockIdx.x * 256 + threadIdx.x;
  if (i >= n4) return;
  float4 v = ((const float4*)in)[i];
  u16x4 o;
  o[0] = f2bf(v.x); o[1] = f2bf(v.y); o[2] = f2bf(v.z); o[3] = f2bf(v.w);
  *(u16x4*)&out[i * 4] = o;
}

// ---------- merged weight transpose-cast (vectorized; proven in R11/R12) ----------
__global__ __launch_bounds__(256) void wcast(
    const float* __restrict__ wqd, const float* __restrict__ wqn,
    const float* __restrict__ wqr, const float* __restrict__ wkd,
    const float* __restrict__ wvu, const float* __restrict__ wkn,
    const float* __restrict__ wkr, const float* __restrict__ wo,
    u16* __restrict__ W1t, u16* __restrict__ Wqt,
    u16* __restrict__ Wkvt, u16* __restrict__ Wot) {
  __shared__ float tile[64][65];
  const int bid = blockIdx.x;
  const float* W; u16* Wt; int K, N, lid;
  if (bid < 768)       { W = wqd; Wt = W1t;                 K = 2048; N = 1536; lid = bid; }
  else if (bid < 1024) { W = wkd; Wt = W1t + 1536ull * 2048; K = 2048; N = 512;  lid = bid - 768; }
  else if (bid < 1792) { W = wqn; Wt = Wqt;                 K = 1536; N = 2048; lid = bid - 1024; }
  else if (bid < 2176) { W = wqr; Wt = Wqt + 2048ull * 1536; K = 1536; N = 1024; lid = bid - 1792; }
  else if (bid < 2432) { W = wkn; Wt = Wkvt;                K = 512;  N = 2048; lid = bid - 2176; }
  else if (bid < 2560) { W = wkr; Wt = Wkvt + 2048ull * 512; K = 512;  N = 1024; lid = bid - 2432; }
  else if (bid < 2944) { W = wvu; Wt = Wkvt + 3072ull * 512; K = 512;  N = 3072; lid = bid - 2560; }
  else                 { W = wo;  Wt = Wot;                 K = 3072; N = 2048; lid = bid - 2944; }
  const int kb = K >> 6;
  const int k0 = (lid % kb) * 64, n0 = (lid / kb) * 64;
  const int tid = threadIdx.x;
  const int lane4 = (tid & 15) * 4, grp = tid >> 4;
#pragma unroll
  for (int p = 0; p < 4; ++p) {
    int r = p * 16 + grp;
    float4 v = *(const float4*)&W[(size_t)(k0 + r) * N + n0 + lane4];
    tile[r][lane4]     = v.x;
    tile[r][lane4 + 1] = v.y;
    tile[r][lane4 + 2] = v.z;
    tile[r][lane4 + 3] = v.w;
  }
  __syncthreads();
  const int n = tid >> 2, ks = (tid & 3) * 16;
  short8 s0, s1;
#pragma unroll
  for (int j = 0; j < 8; ++j) s0[j] = (short)f2bf(tile[ks + j][n]);
#pragma unroll
  for (int j = 0; j < 8; ++j) s1[j] = (short)f2bf(tile[ks + 8 + j][n]);
  u16* dst = Wt + (size_t)(n0 + n) * K + k0 + ks;
  *(short8*)dst = s0;
  *(short8*)(dst + 8) = s1;
}

// ---------- phased GEMM (R10 exact) ----------
// EPI 0: bf16 -> out0 (ldc)
// EPI 1: c<2048 -> out0 col (c>>7)*192+(c&127) (ldc); else out1 col c-2048 (ld 1024)
// EPI 2: fp32 -> out0 (ldc)
// EPI 3: n0<3072 -> EPI1-style; n0>=3072 -> V^T [b][h][d][t] -> out2
template <int EPI>
__global__ __launch_bounds__(512, 2) void gemm_p8(const u16* __restrict__ A, int lda,
                                                  const u16* __restrict__ Bt, int ldb,
                                                  void* __restrict__ out0,
                                                  void* __restrict__ out1,
                                                  void* __restrict__ out2, int ldc,
                                                  int K) {
  __shared__ char smem[147456];
  const int tid = threadIdx.x;
  const int w = tid >> 6, l = tid & 63;
  const int wr = w >> 2, wc = w & 3;
  const int lr = l & 15, hi = l >> 4, lg4 = hi * 4;

  const int nbx = gridDim.x;
  int id = blockIdx.y * nbx + blockIdx.x;
  int cpx = (nbx * gridDim.y) >> 3;
  int sid = (id & 7) * cpx + (id >> 3);
  const int m0 = (sid % nbx) * 128, n0 = (sid / nbx) * 256;

  const u16* asrc[2];
  const u16* bsrc[4];
#pragma unroll
  for (int j = 0; j < 2; ++j) {
    int lin = j * 8192 + tid * 16;
    int row = lin >> 7, colb = lin & 127;
    asrc[j] = A + (size_t)(m0 + row) * lda + ((colb ^ ((row & 7) << 4)) >> 1);
  }
#pragma unroll
  for (int j = 0; j < 4; ++j) {
    int lin = j * 8192 + tid * 16;
    int row = lin >> 7, colb = lin & 127;
    bsrc[j] = Bt + (size_t)(n0 + row) * ldb + ((colb ^ ((row & 7) << 4)) >> 1);
  }

  int aoff[4], boff[4];
#pragma unroll
  for (int m = 0; m < 4; ++m) {
    int row = wr * 64 + m * 16 + lr;
    aoff[m] = row * 128 + ((hi * 16) ^ ((row & 7) << 4));
  }
#pragma unroll
  for (int n = 0; n < 4; ++n) {
    int row = wc * 64 + n * 16 + lr;
    boff[n] = 16384 + row * 128 + ((hi * 16) ^ ((row & 7) << 4));
  }

  auto STAGE0 = [&](int kt) {
    char* buf = smem + 49152 * (kt % 3) + (w << 10);
    const int ke = kt << 6;
    gload_lds16(asrc[0] + ke, buf);
    gload_lds16(asrc[1] + ke, buf + 8192);
    gload_lds16(bsrc[0] + ke, buf + 16384);
    gload_lds16(bsrc[1] + ke, buf + 24576);
  };
  auto STAGE1 = [&](int kt) {
    char* buf = smem + 49152 * (kt % 3) + (w << 10);
    const int ke = kt << 6;
    gload_lds16(bsrc[2] + ke, buf + 32768);
    gload_lds16(bsrc[3] + ke, buf + 40960);
  };

  f32x4 acc[4][4] = {};
  const int NT = K >> 6;

  STAGE0(0); STAGE1(0); STAGE0(1); STAGE1(1);

  for (int kt = 0; kt < NT; ++kt) {
    if (kt < NT - 1) { VMCNT(6); } else { VMCNT(0); }
    __builtin_amdgcn_s_barrier();
    MEMFENCE;
    const char* buf = smem + 49152 * (kt % 3);
    {
      short8 a0[4], b0[4];
#pragma unroll
      for (int m = 0; m < 4; ++m) a0[m] = *(const short8*)(buf + aoff[m]);
#pragma unroll
      for (int n = 0; n < 4; ++n) b0[n] = *(const short8*)(buf + boff[n]);
      if (kt + 2 < NT) STAGE0(kt + 2);
      LGKMCNT(0);
      __builtin_amdgcn_sched_barrier(0);
      __builtin_amdgcn_s_setprio(1);
#pragma unroll
      for (int m = 0; m < 4; ++m)
#pragma unroll
        for (int n = 0; n < 4; ++n) acc[m][n] = mfma16(a0[m], b0[n], acc[m][n]);
      __builtin_amdgcn_s_setprio(0);
    }
    MEMFENCE;
    __builtin_amdgcn_s_barrier();
    MEMFENCE;
    {
      short8 a1[4], b1[4];
#pragma unroll
      for (int m = 0; m < 4; ++m) a1[m] = *(const short8*)(buf + (aoff[m] ^ 64));
#pragma unroll
      for (int n = 0; n < 4; ++n) b1[n] = *(const short8*)(buf + (boff[n] ^ 64));
      if (kt + 2 < NT) STAGE1(kt + 2);
      LGKMCNT(0);
      __builtin_amdgcn_sched_barrier(0);
      __builtin_amdgcn_s_setprio(1);
#pragma unroll
      for (int m = 0; m < 4; ++m)
#pragma unroll
        for (int n = 0; n < 4; ++n) acc[m][n] = mfma16(a1[m], b1[n], acc[m][n]);
      __builtin_amdgcn_s_setprio(0);
    }
    MEMFENCE;
  }

  if (EPI == 3 && n0 >= 3072) {
    __syncthreads();
    u16* ldt = (u16*)smem;  // [256][136]
#pragma unroll
    for (int m = 0; m < 4; ++m)
#pragma unroll
      for (int n = 0; n < 4; ++n)
#pragma unroll
        for (int j = 0; j < 4; ++j)
          ldt[(wc * 64 + n * 16 + lr) * 136 + (wr * 64 + m * 16 + lg4 + j)] =
              f2bf(acc[m][n][j]);
    __syncthreads();
    const int b = m0 >> 10, tloc = m0 & 1023, n0v = n0 - 3072;
#pragma unroll
    for (int i = 0; i < 8; ++i) {
      int lin = i * 512 + tid;
      int col = lin >> 4, t16 = lin & 15;
      int cg = n0v + col;
      int h = (unsigned)cg / 192u, d = cg - h * 192;
      short8 vv = *(const short8*)&ldt[col * 136 + t16 * 8];
      *(short8*)((u16*)out2 + ((size_t)(b * 16 + h) * 192 + d) * 1024 + tloc + t16 * 8) = vv;
    }
    return;
  }
#pragma unroll
  for (int m = 0; m < 4; ++m)
#pragma unroll
    for (int n = 0; n < 4; ++n)
#pragma unroll
      for (int j = 0; j < 4; ++j) {
        int r = m0 + wr * 64 + m * 16 + lg4 + j;
        int c = n0 + wc * 64 + n * 16 + lr;
        float v = acc[m][n][j];
        if (EPI == 0) {
          ((u16*)out0)[(size_t)r * ldc + c] = f2bf(v);
        } else if (EPI == 1 || EPI == 3) {
          if (c < 2048) {
            int cc = (c >> 7) * 192 + (c & 127);
            ((u16*)out0)[(size_t)r * ldc + cc] = f2bf(v);
          } else {
            ((u16*)out1)[(size_t)r * 1024 + (c - 2048)] = f2bf(v);
          }
        } else {
          ((float*)out0)[(size_t)r * ldc + c] = v;
        }
      }
}

// ---------- RoPE (R10 exact) ----------
__global__ __launch_bounds__(256) void rope_k(const u16* __restrict__ qsrc,
                                              const u16* __restrict__ ksrc,
                                              u16* __restrict__ qdst,
                                              u16* __restrict__ kdst) {
  int idx = blockIdx.x * 256 + threadIdx.x;
  int row = idx >> 9;
  int rem = idx & 511;
  int h = rem >> 5, i = rem & 31;
  int tpos = row & 1023;
  float inv = exp2f(-(float)i * 0.4152410118609203f);  // 10000^(-i/32)
  float f = (float)tpos * inv;
  float s, c;
  sincosf(f, &s, &c);
  size_t si = (size_t)row * 1024 + h * 64 + 2 * i;
  size_t o = (size_t)row * 3072 + h * 192 + 128 + 2 * i;
  {
    float x1 = bf2f(qsrc[si]), x2 = bf2f(qsrc[si + 1]);
    qdst[o]     = f2bf(x1 * c - x2 * s);
    qdst[o + 1] = f2bf(x1 * s + x2 * c);
  }
  {
    float x1 = bf2f(ksrc[si]), x2 = bf2f(ksrc[si + 1]);
    kdst[o]     = f2bf(x1 * c - x2 * s);
    kdst[o + 1] = f2bf(x1 * s + x2 * c);
  }
}

// ---------- flash attention: R10 exact (KVBLK=32, ring-2, XCD-local grid) ----------
__global__ __launch_bounds__(256, 2) void attn_kernel(const u16* __restrict__ Q,
                                                      const u16* __restrict__ K,
                                                      const u16* __restrict__ Vt,
                                                      u16* __restrict__ O) {
  __shared__ char smem[57344];
  const int t = threadIdx.x, w = t >> 6, l = t & 63;
  const int lr = l & 15, hi = l >> 4;
  const int y = blockIdx.y;
  const int qidx = (y < 4) ? 2 * y : 15 - 2 * y;   // pairs (y,y+4) sum to 7
  const int qb = qidx * 128;
  const int bh = blockIdx.x;
  const int b = bh >> 4, h = bh & 15;
  const int wq0 = qb + w * 32;
  const size_t rs = 3072;
  const u16* Qg = Q + ((size_t)(b * 1024 + qb)) * rs + h * 192;
  const char* Kg = (const char*)(K + ((size_t)b * 1024) * rs + h * 192);
  const char* Vg = (const char*)(Vt + (size_t)(b * 16 + h) * 192 * 1024);  // [d][t]
  u16* Og = O + ((size_t)(b * 1024 + qb)) * rs + h * 192;

  char* psw = smem + 49152 + w * 2048;
  const int kswz = (lr & 7) << 4;
  const int pswz = (lr & 3) << 4;

  short8 qfr[2][6];
#pragma unroll
  for (int qf = 0; qf < 2; ++qf)
#pragma unroll
    for (int dc = 0; dc < 6; ++dc)
      qfr[qf][dc] = *(const short8*)(Qg + (size_t)(w * 32 + qf * 16 + lr) * rs + dc * 32 + hi * 8);

  const char* kptr[3];
#pragma unroll
  for (int i = 0; i < 3; ++i) {
    int lin = (i * 4 + w) * 1024 + l * 16;
    int row = lin / 384;
    int col = lin % 384;
    kptr[i] = Kg + (size_t)row * 6144 + (col ^ ((row & 7) << 4));
  }
  const char* vptr[3];
#pragma unroll
  for (int i = 0; i < 3; ++i) {
    int lin = (i * 4 + w) * 1024 + l * 16;
    int row = lin >> 6;
    int col = lin & 63;
    vptr[i] = Vg + (size_t)row * 2048 + (col ^ ((row & 3) << 4));
  }

  f32x4 o[12][2] = {};
  float m[2] = {-1e30f, -1e30f}, ls[2] = {0.f, 0.f};
  const float scale = 0.07216878364870323f;  // 1/sqrt(192)
  const int nkv = 4 * (qidx + 1);

  auto STAGE = [&](int kt) {
    char* kb = smem + (kt & 1) * 24576;
    char* vb = kb + 12288;
#pragma unroll
    for (int i = 0; i < 3; ++i) {
      gload_lds16(kptr[i] + (size_t)kt * 196608, kb + (i * 4 + w) * 1024);
      gload_lds16(vptr[i] + (size_t)kt * 64,     vb + (i * 4 + w) * 1024);
    }
  };

  STAGE(0);
  for (int kt = 0; kt < nkv; ++kt) {
    if (kt + 1 < nkv) { STAGE(kt + 1); VMCNT(6); }
    else              { VMCNT(0); }
    __builtin_amdgcn_s_barrier();
    MEMFENCE;
    const int kv0 = kt << 5;
    const char* ks = smem + (kt & 1) * 24576;
    const char* vs = ks + 12288;

    if (kv0 <= wq0) {
      f32x4 st[2][2] = {};
#pragma unroll
      for (int dc = 0; dc < 6; ++dc) {
        const int kin = (dc * 64 + hi * 16) ^ kswz;
        short8 ka0 = *(const short8*)(ks + lr * 384 + kin);
        short8 ka1 = *(const short8*)(ks + (16 + lr) * 384 + kin);
        st[0][0] = mfma16(ka0, qfr[0][dc], st[0][0]);
        st[0][1] = mfma16(ka0, qfr[1][dc], st[0][1]);
        st[1][0] = mfma16(ka1, qfr[0][dc], st[1][0]);
        st[1][1] = mfma16(ka1, qfr[1][dc], st[1][1]);
      }

      const bool needmask = (kv0 + 31 > wq0);
      float mt[2];
#pragma unroll
      for (int qf = 0; qf < 2; ++qf) {
        const int q = wq0 + qf * 16 + lr;
        float mx = -1e30f;
#pragma unroll
        for (int kf = 0; kf < 2; ++kf)
#pragma unroll
          for (int j = 0; j < 4; ++j) {
            float s = st[kf][qf][j] * scale;
            if (needmask && (kv0 + kf * 16 + hi * 4 + j > q)) s = -1e30f;
            st[kf][qf][j] = s;
            mx = fmaxf(mx, s);
          }
        mx = fmaxf(mx, __shfl_xor(mx, 16));
        mx = fmaxf(mx, __shfl_xor(mx, 32));
        mt[qf] = mx;
      }
      const bool skip = __all((mt[0] <= m[0] + 8.0f) & (mt[1] <= m[1] + 8.0f));
      if (!skip) {
#pragma unroll
        for (int qf = 0; qf < 2; ++qf) {
          float mn = fmaxf(m[qf], mt[qf]);
          float corr = __expf(m[qf] - mn);
          m[qf] = mn;
          ls[qf] *= corr;
#pragma unroll
          for (int nf = 0; nf < 12; ++nf)
#pragma unroll
            for (int j = 0; j < 4; ++j) o[nf][qf][j] *= corr;
        }
      }
#pragma unroll
      for (int qf = 0; qf < 2; ++qf) {
        float sum = 0.f;
        char* pq = psw + (qf * 16 + lr) * 64;
#pragma unroll
        for (int kf = 0; kf < 2; ++kf)
#pragma unroll
          for (int jp = 0; jp < 2; ++jp) {
            float p0 = __expf(st[kf][qf][2 * jp]     - m[qf]);
            float p1 = __expf(st[kf][qf][2 * jp + 1] - m[qf]);
            sum += p0 + p1;
            unsigned pk = (unsigned)f2bf(p0) | ((unsigned)f2bf(p1) << 16);
            int kb = 2 * (kf * 16 + hi * 4 + 2 * jp);
            *(unsigned*)(pq + (kb ^ pswz)) = pk;
          }
        sum += __shfl_xor(sum, 16);
        sum += __shfl_xor(sum, 32);
        ls[qf] += sum;
      }
      asm volatile("s_waitcnt lgkmcnt(0)" ::: "memory");
      __builtin_amdgcn_sched_barrier(0);

      short8 pb0 = *(const short8*)(psw + lr * 64 + ((hi * 16) ^ pswz));
      short8 pb1 = *(const short8*)(psw + (16 + lr) * 64 + ((hi * 16) ^ pswz));
#pragma unroll
      for (int nf = 0; nf < 12; ++nf) {
        short8 va = *(const short8*)(vs + (nf * 16 + lr) * 64 + ((hi * 16) ^ pswz));
        o[nf][0] = mfma16(va, pb0, o[nf][0]);
        o[nf][1] = mfma16(va, pb1, o[nf][1]);
      }
    }
    MEMFENCE;
    __builtin_amdgcn_s_barrier();
  }

#pragma unroll
  for (int qf = 0; qf < 2; ++qf) {
    float inv = 1.0f / ls[qf];
    char* ob = smem + (w * 32 + qf * 16 + lr) * 384;
#pragma unroll
    for (int nf = 0; nf < 12; ++nf)
#pragma unroll
      for (int j = 0; j < 4; ++j)
        *(u16*)(ob + ((nf * 32 + hi * 8 + 2 * j) ^ kswz)) = f2bf(o[nf][qf][j] * inv);
  }
  __syncthreads();
#pragma unroll
  for (int i = 0; i < 12; ++i) {
    int idx = i * 256 + t;
    int row = idx / 24;
    int c16 = idx % 24;
    short8 vv = *(const short8*)(smem + row * 384 + ((c16 * 16) ^ ((row & 7) << 4)));
    *(short8*)((char*)Og + (size_t)row * 6144 + c16 * 16) = vv;
  }
}

// ---------- launch ----------
extern "C" void kernel_launch(void* const* d_in, const int* in_sizes, int n_in,
                              void* d_out, int out_size, void* d_ws, size_t ws_size,
                              hipStream_t stream) {
  const float* x   = (const float*)d_in[0];
  const float* wqd = (const float*)d_in[1];
  const float* wqn = (const float*)d_in[2];
  const float* wqr = (const float*)d_in[3];
  const float* wkd = (const float*)d_in[4];
  const float* wvu = (const float*)d_in[5];
  const float* wkn = (const float*)d_in[6];
  const float* wkr = (const float*)d_in[7];
  const float* wo  = (const float*)d_in[8];

  char* ws = (char*)d_ws;
  size_t off = 0;
  auto alloc = [&](size_t bytes) {
    char* p = ws + off;
    off += (bytes + 255) & ~(size_t)255;
    return p;
  };
  u16* xb   = (u16*)alloc(8388608ull * 2);       // x bf16
  u16* W1t  = (u16*)alloc(2048ull * 2048 * 2);   // [wq_down|wkv_down]^T
  u16* Wqt  = (u16*)alloc(3072ull * 1536 * 2);   // [wq_nope|wq_rope]^T
  u16* Wkvt = (u16*)alloc(6144ull * 512 * 2);    // [wk_nope|wk_rope|wv_up]^T
  u16* Wot  = (u16*)alloc(2048ull * 3072 * 2);
  u16* lat  = (u16*)alloc(4096ull * 2048 * 2);   // [q_latent | kv_latent]
  u16* Qb   = (u16*)alloc(4096ull * 3072 * 2);
  u16* Kb   = (u16*)alloc(4096ull * 3072 * 2);
  u16* Vt   = (u16*)alloc(4096ull * 3072 * 2);   // V^T [b][h][d][t]
  u16* AO   = (u16*)alloc(4096ull * 3072 * 2);
  u16* qrt  = (u16*)alloc(4096ull * 1024 * 2);
  u16* krt  = (u16*)alloc(4096ull * 1024 * 2);

  castk<<<8192, 256, 0, stream>>>(x, xb, 2097152);

  wcast<<<4480, 256, 0, stream>>>(wqd, wqn, wqr, wkd, wvu, wkn, wkr, wo,
                                  W1t, Wqt, Wkvt, Wot);

  // latent = x @ [wq_down|wkv_down]   (M=4096, N=2048, K=2048)
  gemm_p8<0><<<dim3(32, 8), 512, 0, stream>>>(xb, 2048, W1t, 2048, lat, nullptr, nullptr, 2048, 2048);
  // q fused: nope -> Qb (remap), rope -> qrt   (N=3072, K=1536)
  gemm_p8<1><<<dim3(32, 12), 512, 0, stream>>>(lat, 2048, Wqt, 1536, Qb, qrt, nullptr, 3072, 1536);
  // kv fused: k_nope -> Kb, k_rope -> krt, v -> Vt   (N=6144, K=512)
  gemm_p8<3><<<dim3(32, 24), 512, 0, stream>>>(lat + 1536, 2048, Wkvt, 512, Kb, krt, Vt, 3072, 512);

  rope_k<<<8192, 256, 0, stream>>>(qrt, krt, Qb, Kb);

  attn_kernel<<<dim3(64, 8), 256, 0, stream>>>(Qb, Kb, Vt, AO);

  // out = AO @ wo (fp32 out)   (N=2048, K=3072)
  gemm_p8<2><<<dim3(32, 8), 512, 0, stream>>>(AO, 3072, Wot, 3072, d_out, nullptr, nullptr, 2048, 3072);
}

// Round 16
// 270.185 us; speedup vs baseline: 1.0020x; 1.0020x over previous
//
#include <hip/hip_runtime.h>

// ---------- types ----------
typedef unsigned short u16;
typedef __bf16  bf16x8 __attribute__((ext_vector_type(8)));
typedef short   short8 __attribute__((ext_vector_type(8)));
typedef float   f32x4  __attribute__((ext_vector_type(4)));
typedef u16     u16x4  __attribute__((ext_vector_type(4)));

__device__ __forceinline__ u16 f2bf(float f) {
  unsigned b = __builtin_bit_cast(unsigned, f);
  b += 0x7fffu + ((b >> 16) & 1u);          // round-to-nearest-even
  return (u16)(b >> 16);
}
__device__ __forceinline__ float bf2f(u16 u) {
  return __builtin_bit_cast(float, (unsigned)u << 16);
}
__device__ __forceinline__ f32x4 mfma16(short8 a, short8 b, f32x4 c) {
  return __builtin_amdgcn_mfma_f32_16x16x32_bf16(
      __builtin_bit_cast(bf16x8, a), __builtin_bit_cast(bf16x8, b), c, 0, 0, 0);
}
__device__ __forceinline__ void gload_lds16(const void* g, void* l) {
  __builtin_amdgcn_global_load_lds(
      (const __attribute__((address_space(1))) void*)g,
      (__attribute__((address_space(3))) void*)l, 16, 0, 0);
}

#define VMCNT(n) asm volatile("s_waitcnt vmcnt(" #n ")" ::: "memory")
#define LGKMCNT(n) asm volatile("s_waitcnt lgkmcnt(" #n ")" ::: "memory")
#define MEMFENCE asm volatile("" ::: "memory")

// ---------- cast x -> bf16 ----------
__global__ __launch_bounds__(256) void castk(const float* __restrict__ in,
                                             u16* __restrict__ out, int n4) {
  int i = blockIdx.x * 256 + threadIdx.x;
  if (i >= n4) return;
  float4 v = ((const float4*)in)[i];
  u16x4 o;
  o[0] = f2bf(v.x); o[1] = f2bf(v.y); o[2] = f2bf(v.z); o[3] = f2bf(v.w);
  *(u16x4*)&out[i * 4] = o;
}

// ---------- merged weight transpose-cast (vectorized; proven in R11/R12) ----------
__global__ __launch_bounds__(256) void wcast(
    const float* __restrict__ wqd, const float* __restrict__ wqn,
    const float* __restrict__ wqr, const float* __restrict__ wkd,
    const float* __restrict__ wvu, const float* __restrict__ wkn,
    const float* __restrict__ wkr, const float* __restrict__ wo,
    u16* __restrict__ W1t, u16* __restrict__ Wqt,
    u16* __restrict__ Wkvt, u16* __restrict__ Wot) {
  __shared__ float tile[64][65];
  const int bid = blockIdx.x;
  const float* W; u16* Wt; int K, N, lid;
  if (bid < 768)       { W = wqd; Wt = W1t;                 K = 2048; N = 1536; lid = bid; }
  else if (bid < 1024) { W = wkd; Wt = W1t + 1536ull * 2048; K = 2048; N = 512;  lid = bid - 768; }
  else if (bid < 1792) { W = wqn; Wt = Wqt;                 K = 1536; N = 2048; lid = bid - 1024; }
  else if (bid < 2176) { W = wqr; Wt = Wqt + 2048ull * 1536; K = 1536; N = 1024; lid = bid - 1792; }
  else if (bid < 2432) { W = wkn; Wt = Wkvt;                K = 512;  N = 2048; lid = bid - 2176; }
  else if (bid < 2560) { W = wkr; Wt = Wkvt + 2048ull * 512; K = 512;  N = 1024; lid = bid - 2432; }
  else if (bid < 2944) { W = wvu; Wt = Wkvt + 3072ull * 512; K = 512;  N = 3072; lid = bid - 2560; }
  else                 { W = wo;  Wt = Wot;                 K = 3072; N = 2048; lid = bid - 2944; }
  const int kb = K >> 6;
  const int k0 = (lid % kb) * 64, n0 = (lid / kb) * 64;
  const int tid = threadIdx.x;
  const int lane4 = (tid & 15) * 4, grp = tid >> 4;
#pragma unroll
  for (int p = 0; p < 4; ++p) {
    int r = p * 16 + grp;
    float4 v = *(const float4*)&W[(size_t)(k0 + r) * N + n0 + lane4];
    tile[r][lane4]     = v.x;
    tile[r][lane4 + 1] = v.y;
    tile[r][lane4 + 2] = v.z;
    tile[r][lane4 + 3] = v.w;
  }
  __syncthreads();
  const int n = tid >> 2, ks = (tid & 3) * 16;
  short8 s0, s1;
#pragma unroll
  for (int j = 0; j < 8; ++j) s0[j] = (short)f2bf(tile[ks + j][n]);
#pragma unroll
  for (int j = 0; j < 8; ++j) s1[j] = (short)f2bf(tile[ks + 8 + j][n]);
  u16* dst = Wt + (size_t)(n0 + n) * K + k0 + ks;
  *(short8*)dst = s0;
  *(short8*)(dst + 8) = s1;
}

// ---------- phased GEMM (R10 exact) ----------
// EPI 0: bf16 -> out0 (ldc)
// EPI 1: c<2048 -> out0 col (c>>7)*192+(c&127) (ldc); else out1 col c-2048 (ld 1024)
// EPI 2: fp32 -> out0 (ldc)
// EPI 3: n0<3072 -> EPI1-style; n0>=3072 -> V^T [b][h][d][t] -> out2
template <int EPI>
__global__ __launch_bounds__(512, 2) void gemm_p8(const u16* __restrict__ A, int lda,
                                                  const u16* __restrict__ Bt, int ldb,
                                                  void* __restrict__ out0,
                                                  void* __restrict__ out1,
                                                  void* __restrict__ out2, int ldc,
                                                  int K) {
  __shared__ char smem[147456];
  const int tid = threadIdx.x;
  const int w = tid >> 6, l = tid & 63;
  const int wr = w >> 2, wc = w & 3;
  const int lr = l & 15, hi = l >> 4, lg4 = hi * 4;

  const int nbx = gridDim.x;
  int id = blockIdx.y * nbx + blockIdx.x;
  int cpx = (nbx * gridDim.y) >> 3;
  int sid = (id & 7) * cpx + (id >> 3);
  const int m0 = (sid % nbx) * 128, n0 = (sid / nbx) * 256;

  const u16* asrc[2];
  const u16* bsrc[4];
#pragma unroll
  for (int j = 0; j < 2; ++j) {
    int lin = j * 8192 + tid * 16;
    int row = lin >> 7, colb = lin & 127;
    asrc[j] = A + (size_t)(m0 + row) * lda + ((colb ^ ((row & 7) << 4)) >> 1);
  }
#pragma unroll
  for (int j = 0; j < 4; ++j) {
    int lin = j * 8192 + tid * 16;
    int row = lin >> 7, colb = lin & 127;
    bsrc[j] = Bt + (size_t)(n0 + row) * ldb + ((colb ^ ((row & 7) << 4)) >> 1);
  }

  int aoff[4], boff[4];
#pragma unroll
  for (int m = 0; m < 4; ++m) {
    int row = wr * 64 + m * 16 + lr;
    aoff[m] = row * 128 + ((hi * 16) ^ ((row & 7) << 4));
  }
#pragma unroll
  for (int n = 0; n < 4; ++n) {
    int row = wc * 64 + n * 16 + lr;
    boff[n] = 16384 + row * 128 + ((hi * 16) ^ ((row & 7) << 4));
  }

  auto STAGE0 = [&](int kt) {
    char* buf = smem + 49152 * (kt % 3) + (w << 10);
    const int ke = kt << 6;
    gload_lds16(asrc[0] + ke, buf);
    gload_lds16(asrc[1] + ke, buf + 8192);
    gload_lds16(bsrc[0] + ke, buf + 16384);
    gload_lds16(bsrc[1] + ke, buf + 24576);
  };
  auto STAGE1 = [&](int kt) {
    char* buf = smem + 49152 * (kt % 3) + (w << 10);
    const int ke = kt << 6;
    gload_lds16(bsrc[2] + ke, buf + 32768);
    gload_lds16(bsrc[3] + ke, buf + 40960);
  };

  f32x4 acc[4][4] = {};
  const int NT = K >> 6;

  STAGE0(0); STAGE1(0); STAGE0(1); STAGE1(1);

  for (int kt = 0; kt < NT; ++kt) {
    if (kt < NT - 1) { VMCNT(6); } else { VMCNT(0); }
    __builtin_amdgcn_s_barrier();
    MEMFENCE;
    const char* buf = smem + 49152 * (kt % 3);
    {
      short8 a0[4], b0[4];
#pragma unroll
      for (int m = 0; m < 4; ++m) a0[m] = *(const short8*)(buf + aoff[m]);
#pragma unroll
      for (int n = 0; n < 4; ++n) b0[n] = *(const short8*)(buf + boff[n]);
      if (kt + 2 < NT) STAGE0(kt + 2);
      LGKMCNT(0);
      __builtin_amdgcn_sched_barrier(0);
      __builtin_amdgcn_s_setprio(1);
#pragma unroll
      for (int m = 0; m < 4; ++m)
#pragma unroll
        for (int n = 0; n < 4; ++n) acc[m][n] = mfma16(a0[m], b0[n], acc[m][n]);
      __builtin_amdgcn_s_setprio(0);
    }
    MEMFENCE;
    __builtin_amdgcn_s_barrier();
    MEMFENCE;
    {
      short8 a1[4], b1[4];
#pragma unroll
      for (int m = 0; m < 4; ++m) a1[m] = *(const short8*)(buf + (aoff[m] ^ 64));
#pragma unroll
      for (int n = 0; n < 4; ++n) b1[n] = *(const short8*)(buf + (boff[n] ^ 64));
      if (kt + 2 < NT) STAGE1(kt + 2);
      LGKMCNT(0);
      __builtin_amdgcn_sched_barrier(0);
      __builtin_amdgcn_s_setprio(1);
#pragma unroll
      for (int m = 0; m < 4; ++m)
#pragma unroll
        for (int n = 0; n < 4; ++n) acc[m][n] = mfma16(a1[m], b1[n], acc[m][n]);
      __builtin_amdgcn_s_setprio(0);
    }
    MEMFENCE;
  }

  if (EPI == 3 && n0 >= 3072) {
    __syncthreads();
    u16* ldt = (u16*)smem;  // [256][136]
#pragma unroll
    for (int m = 0; m < 4; ++m)
#pragma unroll
      for (int n = 0; n < 4; ++n)
#pragma unroll
        for (int j = 0; j < 4; ++j)
          ldt[(wc * 64 + n * 16 + lr) * 136 + (wr * 64 + m * 16 + lg4 + j)] =
              f2bf(acc[m][n][j]);
    __syncthreads();
    const int b = m0 >> 10, tloc = m0 & 1023, n0v = n0 - 3072;
#pragma unroll
    for (int i = 0; i < 8; ++i) {
      int lin = i * 512 + tid;
      int col = lin >> 4, t16 = lin & 15;
      int cg = n0v + col;
      int h = (unsigned)cg / 192u, d = cg - h * 192;
      short8 vv = *(const short8*)&ldt[col * 136 + t16 * 8];
      *(short8*)((u16*)out2 + ((size_t)(b * 16 + h) * 192 + d) * 1024 + tloc + t16 * 8) = vv;
    }
    return;
  }
#pragma unroll
  for (int m = 0; m < 4; ++m)
#pragma unroll
    for (int n = 0; n < 4; ++n)
#pragma unroll
      for (int j = 0; j < 4; ++j) {
        int r = m0 + wr * 64 + m * 16 + lg4 + j;
        int c = n0 + wc * 64 + n * 16 + lr;
        float v = acc[m][n][j];
        if (EPI == 0) {
          ((u16*)out0)[(size_t)r * ldc + c] = f2bf(v);
        } else if (EPI == 1 || EPI == 3) {
          if (c < 2048) {
            int cc = (c >> 7) * 192 + (c & 127);
            ((u16*)out0)[(size_t)r * ldc + cc] = f2bf(v);
          } else {
            ((u16*)out1)[(size_t)r * 1024 + (c - 2048)] = f2bf(v);
          }
        } else {
          ((float*)out0)[(size_t)r * ldc + c] = v;
        }
      }
}

// ---------- RoPE (R10 exact) ----------
__global__ __launch_bounds__(256) void rope_k(const u16* __restrict__ qsrc,
                                              const u16* __restrict__ ksrc,
                                              u16* __restrict__ qdst,
                                              u16* __restrict__ kdst) {
  int idx = blockIdx.x * 256 + threadIdx.x;
  int row = idx >> 9;
  int rem = idx & 511;
  int h = rem >> 5, i = rem & 31;
  int tpos = row & 1023;
  float inv = exp2f(-(float)i * 0.4152410118609203f);  // 10000^(-i/32)
  float f = (float)tpos * inv;
  float s, c;
  sincosf(f, &s, &c);
  size_t si = (size_t)row * 1024 + h * 64 + 2 * i;
  size_t o = (size_t)row * 3072 + h * 192 + 128 + 2 * i;
  {
    float x1 = bf2f(qsrc[si]), x2 = bf2f(qsrc[si + 1]);
    qdst[o]     = f2bf(x1 * c - x2 * s);
    qdst[o + 1] = f2bf(x1 * s + x2 * c);
  }
  {
    float x1 = bf2f(ksrc[si]), x2 = bf2f(ksrc[si + 1]);
    kdst[o]     = f2bf(x1 * c - x2 * s);
    kdst[o + 1] = f2bf(x1 * s + x2 * c);
  }
}

// ---------- flash attention: R10 exact (KVBLK=32, ring-2, XCD-local grid) ----------
__global__ __launch_bounds__(256, 2) void attn_kernel(const u16* __restrict__ Q,
                                                      const u16* __restrict__ K,
                                                      const u16* __restrict__ Vt,
                                                      u16* __restrict__ O) {
  __shared__ char smem[57344];
  const int t = threadIdx.x, w = t >> 6, l = t & 63;
  const int lr = l & 15, hi = l >> 4;
  const int y = blockIdx.y;
  const int qidx = (y < 4) ? 2 * y : 15 - 2 * y;   // pairs (y,y+4) sum to 7
  const int qb = qidx * 128;
  const int bh = blockIdx.x;
  const int b = bh >> 4, h = bh & 15;
  const int wq0 = qb + w * 32;
  const size_t rs = 3072;
  const u16* Qg = Q + ((size_t)(b * 1024 + qb)) * rs + h * 192;
  const char* Kg = (const char*)(K + ((size_t)b * 1024) * rs + h * 192);
  const char* Vg = (const char*)(Vt + (size_t)(b * 16 + h) * 192 * 1024);  // [d][t]
  u16* Og = O + ((size_t)(b * 1024 + qb)) * rs + h * 192;

  char* psw = smem + 49152 + w * 2048;
  const int kswz = (lr & 7) << 4;
  const int pswz = (lr & 3) << 4;

  short8 qfr[2][6];
#pragma unroll
  for (int qf = 0; qf < 2; ++qf)
#pragma unroll
    for (int dc = 0; dc < 6; ++dc)
      qfr[qf][dc] = *(const short8*)(Qg + (size_t)(w * 32 + qf * 16 + lr) * rs + dc * 32 + hi * 8);

  const char* kptr[3];
#pragma unroll
  for (int i = 0; i < 3; ++i) {
    int lin = (i * 4 + w) * 1024 + l * 16;
    int row = lin / 384;
    int col = lin % 384;
    kptr[i] = Kg + (size_t)row * 6144 + (col ^ ((row & 7) << 4));
  }
  const char* vptr[3];
#pragma unroll
  for (int i = 0; i < 3; ++i) {
    int lin = (i * 4 + w) * 1024 + l * 16;
    int row = lin >> 6;
    int col = lin & 63;
    vptr[i] = Vg + (size_t)row * 2048 + (col ^ ((row & 3) << 4));
  }

  f32x4 o[12][2] = {};
  float m[2] = {-1e30f, -1e30f}, ls[2] = {0.f, 0.f};
  const float scale = 0.07216878364870323f;  // 1/sqrt(192)
  const int nkv = 4 * (qidx + 1);

  auto STAGE = [&](int kt) {
    char* kb = smem + (kt & 1) * 24576;
    char* vb = kb + 12288;
#pragma unroll
    for (int i = 0; i < 3; ++i) {
      gload_lds16(kptr[i] + (size_t)kt * 196608, kb + (i * 4 + w) * 1024);
      gload_lds16(vptr[i] + (size_t)kt * 64,     vb + (i * 4 + w) * 1024);
    }
  };

  STAGE(0);
  for (int kt = 0; kt < nkv; ++kt) {
    if (kt + 1 < nkv) { STAGE(kt + 1); VMCNT(6); }
    else              { VMCNT(0); }
    __builtin_amdgcn_s_barrier();
    MEMFENCE;
    const int kv0 = kt << 5;
    const char* ks = smem + (kt & 1) * 24576;
    const char* vs = ks + 12288;

    if (kv0 <= wq0) {
      f32x4 st[2][2] = {};
#pragma unroll
      for (int dc = 0; dc < 6; ++dc) {
        const int kin = (dc * 64 + hi * 16) ^ kswz;
        short8 ka0 = *(const short8*)(ks + lr * 384 + kin);
        short8 ka1 = *(const short8*)(ks + (16 + lr) * 384 + kin);
        st[0][0] = mfma16(ka0, qfr[0][dc], st[0][0]);
        st[0][1] = mfma16(ka0, qfr[1][dc], st[0][1]);
        st[1][0] = mfma16(ka1, qfr[0][dc], st[1][0]);
        st[1][1] = mfma16(ka1, qfr[1][dc], st[1][1]);
      }

      const bool needmask = (kv0 + 31 > wq0);
      float mt[2];
#pragma unroll
      for (int qf = 0; qf < 2; ++qf) {
        const int q = wq0 + qf * 16 + lr;
        float mx = -1e30f;
#pragma unroll
        for (int kf = 0; kf < 2; ++kf)
#pragma unroll
          for (int j = 0; j < 4; ++j) {
            float s = st[kf][qf][j] * scale;
            if (needmask && (kv0 + kf * 16 + hi * 4 + j > q)) s = -1e30f;
            st[kf][qf][j] = s;
            mx = fmaxf(mx, s);
          }
        mx = fmaxf(mx, __shfl_xor(mx, 16));
        mx = fmaxf(mx, __shfl_xor(mx, 32));
        mt[qf] = mx;
      }
      const bool skip = __all((mt[0] <= m[0] + 8.0f) & (mt[1] <= m[1] + 8.0f));
      if (!skip) {
#pragma unroll
        for (int qf = 0; qf < 2; ++qf) {
          float mn = fmaxf(m[qf], mt[qf]);
          float corr = __expf(m[qf] - mn);
          m[qf] = mn;
          ls[qf] *= corr;
#pragma unroll
          for (int nf = 0; nf < 12; ++nf)
#pragma unroll
            for (int j = 0; j < 4; ++j) o[nf][qf][j] *= corr;
        }
      }
#pragma unroll
      for (int qf = 0; qf < 2; ++qf) {
        float sum = 0.f;
        char* pq = psw + (qf * 16 + lr) * 64;
#pragma unroll
        for (int kf = 0; kf < 2; ++kf)
#pragma unroll
          for (int jp = 0; jp < 2; ++jp) {
            float p0 = __expf(st[kf][qf][2 * jp]     - m[qf]);
            float p1 = __expf(st[kf][qf][2 * jp + 1] - m[qf]);
            sum += p0 + p1;
            unsigned pk = (unsigned)f2bf(p0) | ((unsigned)f2bf(p1) << 16);
            int kb = 2 * (kf * 16 + hi * 4 + 2 * jp);
            *(unsigned*)(pq + (kb ^ pswz)) = pk;
          }
        sum += __shfl_xor(sum, 16);
        sum += __shfl_xor(sum, 32);
        ls[qf] += sum;
      }
      asm volatile("s_waitcnt lgkmcnt(0)" ::: "memory");
      __builtin_amdgcn_sched_barrier(0);

      short8 pb0 = *(const short8*)(psw + lr * 64 + ((hi * 16) ^ pswz));
      short8 pb1 = *(const short8*)(psw + (16 + lr) * 64 + ((hi * 16) ^ pswz));
#pragma unroll
      for (int nf = 0; nf < 12; ++nf) {
        short8 va = *(const short8*)(vs + (nf * 16 + lr) * 64 + ((hi * 16) ^ pswz));
        o[nf][0] = mfma16(va, pb0, o[nf][0]);
        o[nf][1] = mfma16(va, pb1, o[nf][1]);
      }
    }
    MEMFENCE;
    __builtin_amdgcn_s_barrier();
  }

#pragma unroll
  for (int qf = 0; qf < 2; ++qf) {
    float inv = 1.0f / ls[qf];
    char* ob = smem + (w * 32 + qf * 16 + lr) * 384;
#pragma unroll
    for (int nf = 0; nf < 12; ++nf)
#pragma unroll
      for (int j = 0; j < 4; ++j)
        *(u16*)(ob + ((nf * 32 + hi * 8 + 2 * j) ^ kswz)) = f2bf(o[nf][qf][j] * inv);
  }
  __syncthreads();
#pragma unroll
  for (int i = 0; i < 12; ++i) {
    int idx = i * 256 + t;
    int row = idx / 24;
    int c16 = idx % 24;
    short8 vv = *(const short8*)(smem + row * 384 + ((c16 * 16) ^ ((row & 7) << 4)));
    *(short8*)((char*)Og + (size_t)row * 6144 + c16 * 16) = vv;
  }
}

// ---------- launch ----------
extern "C" void kernel_launch(void* const* d_in, const int* in_sizes, int n_in,
                              void* d_out, int out_size, void* d_ws, size_t ws_size,
                              hipStream_t stream) {
  const float* x   = (const float*)d_in[0];
  const float* wqd = (const float*)d_in[1];
  const float* wqn = (const float*)d_in[2];
  const float* wqr = (const float*)d_in[3];
  const float* wkd = (const float*)d_in[4];
  const float* wvu = (const float*)d_in[5];
  const float* wkn = (const float*)d_in[6];
  const float* wkr = (const float*)d_in[7];
  const float* wo  = (const float*)d_in[8];

  char* ws = (char*)d_ws;
  size_t off = 0;
  auto alloc = [&](size_t bytes) {
    char* p = ws + off;
    off += (bytes + 255) & ~(size_t)255;
    return p;
  };
  u16* xb   = (u16*)alloc(8388608ull * 2);       // x bf16
  u16* W1t  = (u16*)alloc(2048ull * 2048 * 2);   // [wq_down|wkv_down]^T
  u16* Wqt  = (u16*)alloc(3072ull * 1536 * 2);   // [wq_nope|wq_rope]^T
  u16* Wkvt = (u16*)alloc(6144ull * 512 * 2);    // [wk_nope|wk_rope|wv_up]^T
  u16* Wot  = (u16*)alloc(2048ull * 3072 * 2);
  u16* lat  = (u16*)alloc(4096ull * 2048 * 2);   // [q_latent | kv_latent]
  u16* Qb   = (u16*)alloc(4096ull * 3072 * 2);
  u16* Kb   = (u16*)alloc(4096ull * 3072 * 2);
  u16* Vt   = (u16*)alloc(4096ull * 3072 * 2);   // V^T [b][h][d][t]
  u16* AO   = (u16*)alloc(4096ull * 3072 * 2);
  u16* qrt  = (u16*)alloc(4096ull * 1024 * 2);
  u16* krt  = (u16*)alloc(4096ull * 1024 * 2);

  castk<<<8192, 256, 0, stream>>>(x, xb, 2097152);

  wcast<<<4480, 256, 0, stream>>>(wqd, wqn, wqr, wkd, wvu, wkn, wkr, wo,
                                  W1t, Wqt, Wkvt, Wot);

  // latent = x @ [wq_down|wkv_down]   (M=4096, N=2048, K=2048)
  gemm_p8<0><<<dim3(32, 8), 512, 0, stream>>>(xb, 2048, W1t, 2048, lat, nullptr, nullptr, 2048, 2048);
  // q fused: nope -> Qb (remap), rope -> qrt   (N=3072, K=1536)
  gemm_p8<1><<<dim3(32, 12), 512, 0, stream>>>(lat, 2048, Wqt, 1536, Qb, qrt, nullptr, 3072, 1536);
  // kv fused: k_nope -> Kb, k_rope -> krt, v -> Vt   (N=6144, K=512)
  gemm_p8<3><<<dim3(32, 24), 512, 0, stream>>>(lat + 1536, 2048, Wkvt, 512, Kb, krt, Vt, 3072, 512);

  rope_k<<<8192, 256, 0, stream>>>(qrt, krt, Qb, Kb);

  attn_kernel<<<dim3(64, 8), 256, 0, stream>>>(Qb, Kb, Vt, AO);

  // out = AO @ wo (fp32 out)   (N=2048, K=3072)
  gemm_p8<2><<<dim3(32, 8), 512, 0, stream>>>(AO, 3072, Wot, 3072, d_out, nullptr, nullptr, 2048, 3072);
}